// Round 12
// baseline (91.582 us; speedup 1.0000x reference)
//
#include <hip/hip_runtime.h>
#include <hip/hip_bf16.h>
#include <math.h>

#define T_SEQ 2048
#define C_DIM 768
#define NH    12
#define HD    64
#define QKV_N 2304
#define CH    4          // kv-tiles per attention chunk (split-K)
#define NJOBS 1728       // 12 heads x 144 (qi,chunk) pairs

typedef __attribute__((ext_vector_type(8))) short short8;
typedef __attribute__((ext_vector_type(4))) short short4_t;
typedef __attribute__((ext_vector_type(4))) float f32x4;
typedef __hip_bfloat16 bf16;

static __device__ __forceinline__ unsigned int f2bf(float x) {
    bf16 b = __float2bfloat16(x);
    return (unsigned int)*reinterpret_cast<unsigned short*>(&b);
}
static __device__ __forceinline__ float bf2f(short u) {
    unsigned int v = ((unsigned int)(unsigned short)u) << 16;
    return *reinterpret_cast<float*>(&v);
}

static __device__ __forceinline__ void gload_lds16(const void* g, void* l) {
    __builtin_amdgcn_global_load_lds(
        (const __attribute__((address_space(1))) void*)g,
        (__attribute__((address_space(3))) void*)l, 16, 0, 0);
}

// ---------------- fused prep: convert x | transpose w_qkv | transpose w_proj
//                  | rope tables.  2368 blocks, range-dispatched. -----------
static __device__ __forceinline__ void transpose_tile(
    const float* __restrict__ W, short* __restrict__ Wt, int K, int N,
    int bx, int by, float* tile /* [64][65] */) {
    int k0 = by * 64, n0 = bx * 64;
    int tid = threadIdx.x;
    #pragma unroll
    for (int e = 0; e < 16; ++e) {
        int idx = e * 256 + tid;
        int r = idx >> 6, c = idx & 63;
        tile[r * 65 + c] = W[(size_t)(k0 + r) * N + n0 + c];
    }
    __syncthreads();
    #pragma unroll
    for (int e = 0; e < 16; ++e) {
        int idx = e * 256 + tid;
        int n = idx >> 6, k = idx & 63;
        Wt[(size_t)(n0 + n) * K + k0 + k] = (short)f2bf(tile[k * 65 + n]);
    }
}

__global__ __launch_bounds__(256) void prep_kernel(
    const float* __restrict__ x, const float* __restrict__ w_qkv,
    const float* __restrict__ w_proj, short* __restrict__ xb,
    short* __restrict__ wqkvT, short* __restrict__ wprojT,
    float* __restrict__ ctab, float* __restrict__ stab) {
    __shared__ float tile[64 * 65];
    int b = blockIdx.x;
    int tid = threadIdx.x;
    if (b < 1536) {                       // convert x -> bf16 (1536*1024 elems)
        int idx = (b * 256 + tid) * 4;
        float4 v = *(const float4*)(x + idx);
        short4_t o;
        o[0] = (short)f2bf(v.x); o[1] = (short)f2bf(v.y);
        o[2] = (short)f2bf(v.z); o[3] = (short)f2bf(v.w);
        *(short4_t*)(xb + idx) = o;
    } else if (b < 1968) {                // w_qkv [768][2304] -> [2304][768]
        int i = b - 1536;
        transpose_tile(w_qkv, wqkvT, C_DIM, QKV_N, i % 36, i / 36, tile);
    } else if (b < 2112) {                // w_proj [768][768] -> [768][768]^T
        int i = b - 1968;
        transpose_tile(w_proj, wprojT, C_DIM, C_DIM, i % 12, i / 12, tile);
    } else {                              // rope tables (256 blocks)
        int idx = (b - 2112) * 256 + tid;
        int p = idx >> 5;
        int i = idx & 31;
        float invf = exp2f(-(float)i * (0.03125f * 13.287712379549449f));
        float f = (float)p * invf;
        ctab[idx] = cosf(f);
        stab[idx] = sinf(f);
    }
}

// ---------------- fused QKV GEMM + bias + RoPE + head-split + V-transpose --
// Round-7 structure, BK 64 -> 128: 6 K-steps instead of 12 halves the
// per-step fixed cost (barrier drain), which the R8/R11 experiments showed
// dominates at short K. Grid 288 blocks = 1.125/CU -> the 64 KB LDS does
// not cost occupancy (grid-limited, not LDS-limited). No padding (stride
// 128): b128 reads distribute 8 lanes per 16B-quad = conflict-free floor.
__global__ __launch_bounds__(256) void gemm_qkv_rope_kernel(
    const short* __restrict__ A, const short* __restrict__ Bt,
    const float* __restrict__ bias, const float* __restrict__ ctab,
    const float* __restrict__ stab, short* __restrict__ Qout,
    short* __restrict__ Kout, short* __restrict__ Vtout) {
    __shared__ __align__(16) short smem[32768];   // As 16*128*8 | Bs 16*128*8
    short* As = smem;
    short* Bs = smem + 16384;
    int tid = threadIdx.x;
    int w = tid >> 6, l = tid & 63;
    int lr = l & 15, lg = l >> 4;
    int wm = w >> 1, wn = w & 1;
    int m0 = blockIdx.y * 128, n0 = blockIdx.x * 128;
    const int K = C_DIM;

    f32x4 acc[4][4] = {};

    for (int k0 = 0; k0 < K; k0 += 128) {
        __syncthreads();
        #pragma unroll
        for (int e = 0; e < 8; ++e) {
            int u = w * 8 + e;                 // 0..31
            int kc = u >> 1, r0 = (u & 1) * 64;
            const short* srcA = A  + (size_t)(m0 + r0 + l) * K + k0 + kc * 8;
            const short* srcB = Bt + (size_t)(n0 + r0 + l) * K + k0 + kc * 8;
            gload_lds16(srcA, &As[(kc * 128 + r0) * 8]);
            gload_lds16(srcB, &Bs[(kc * 128 + r0) * 8]);
        }
        __syncthreads();
        #pragma unroll
        for (int ks = 0; ks < 4; ++ks) {
            short8 af[4], bf[4];
            #pragma unroll
            for (int mt = 0; mt < 4; ++mt)
                af[mt] = *(const short8*)&As[((ks * 4 + lg) * 128 + wm * 64 + mt * 16 + lr) * 8];
            #pragma unroll
            for (int nt = 0; nt < 4; ++nt)
                bf[nt] = *(const short8*)&Bs[((ks * 4 + lg) * 128 + wn * 64 + nt * 16 + lr) * 8];
            #pragma unroll
            for (int mt = 0; mt < 4; ++mt)
                #pragma unroll
                for (int nt = 0; nt < 4; ++nt)
                    acc[mt][nt] = __builtin_amdgcn_mfma_f32_16x16x32_bf16(
                        af[mt], bf[nt], acc[mt][nt], 0, 0, 0);
        }
    }

    __syncthreads();   // all waves done with As/Bs before V-scratch reuse

    int nc0 = n0 + wn * 64;            // wave's column base (one head)
    int tensor = nc0 / 768;            // 0=Q 1=K 2=V (uniform per wave)
    int h = (nc0 - tensor * 768) >> 6;
    int t0g = m0 + wm * 64;

    float bv[4];
    #pragma unroll
    for (int nt = 0; nt < 4; ++nt) bv[nt] = bias[nc0 + nt * 16 + lr];

    if (tensor < 2) {
        short* dst = (tensor == 0 ? Qout : Kout) + (size_t)h * T_SEQ * HD;
        float qs = (tensor == 0) ? 0.125f : 1.0f;
        #pragma unroll
        for (int mt = 0; mt < 4; ++mt)
            #pragma unroll
            for (int r = 0; r < 4; ++r) {
                int t = t0g + mt * 16 + lg * 4 + r;
                #pragma unroll
                for (int nt = 0; nt < 2; ++nt) {
                    int i = nt * 16 + lr;          // 0..31
                    float c = ctab[t * 32 + i];
                    float s = stab[t * 32 + i];
                    float lo = acc[mt][nt][r]     + bv[nt];
                    float hi = acc[mt][nt + 2][r] + bv[nt + 2];
                    dst[(size_t)t * HD + i]      = (short)f2bf((lo * c - hi * s) * qs);
                    dst[(size_t)t * HD + i + 32] = (short)f2bf((hi * c + lo * s) * qs);
                }
            }
    } else {
        // V: transpose 64x64 wave tile via per-wave LDS scratch region
        // (w*4096 + 4096 <= 16384, inside the single smem allocation).
        short* S = smem + w * 4096;
        #pragma unroll
        for (int mt = 0; mt < 4; ++mt)
            #pragma unroll
            for (int nt = 0; nt < 4; ++nt) {
                int d = nt * 16 + lr;
                #pragma unroll
                for (int r = 0; r < 4; ++r) {
                    int tl = mt * 16 + lg * 4 + r;
                    float v = acc[mt][nt][r] + bv[nt];
                    S[d * 64 + ((tl & 7) | (((tl >> 3) ^ (d & 7)) << 3))] =
                        (short)f2bf(v);
                }
            }
        asm volatile("s_waitcnt lgkmcnt(0)" ::: "memory");
        int cc = l & 7, db = l >> 3;
        #pragma unroll
        for (int i = 0; i < 8; ++i) {
            int d = db + i * 8;
            short8 v = *(const short8*)&S[d * 64 + ((cc ^ (d & 7)) << 3)];
            *(short8*)(Vtout + ((size_t)h * HD + d) * T_SEQ + t0g + cc * 8) = v;
        }
    }
}

// ---------------- proj GEMM, 64x64 tile (384 blocks) -----------------------
__global__ __launch_bounds__(256) void gemm_proj_kernel(
    const short* __restrict__ A, const short* __restrict__ Bt,
    const float* __restrict__ bias, float* __restrict__ C) {
    const int K = C_DIM, N = C_DIM;
    __shared__ __align__(16) short As[8 * 66 * 8];
    __shared__ __align__(16) short Bs[8 * 66 * 8];
    int tid = threadIdx.x;
    int w = tid >> 6, l = tid & 63;
    int lr = l & 15, lg = l >> 4;
    int wm = w >> 1, wn = w & 1;
    int m0 = blockIdx.y * 64, n0 = blockIdx.x * 64;

    f32x4 acc[2][2] = {};

    for (int k0 = 0; k0 < K; k0 += 64) {
        __syncthreads();
        #pragma unroll
        for (int e = 0; e < 2; ++e) {
            int kc = w * 2 + e;                 // wave-uniform dest base
            gload_lds16(A  + (size_t)(m0 + l) * K + k0 + kc * 8, &As[kc * 66 * 8]);
            gload_lds16(Bt + (size_t)(n0 + l) * K + k0 + kc * 8, &Bs[kc * 66 * 8]);
        }
        __syncthreads();
        #pragma unroll
        for (int ks = 0; ks < 2; ++ks) {
            short8 af[2], bf[2];
            #pragma unroll
            for (int mt = 0; mt < 2; ++mt)
                af[mt] = *(const short8*)&As[((ks * 4 + lg) * 66 + wm * 32 + mt * 16 + lr) * 8];
            #pragma unroll
            for (int nt = 0; nt < 2; ++nt)
                bf[nt] = *(const short8*)&Bs[((ks * 4 + lg) * 66 + wn * 32 + nt * 16 + lr) * 8];
            #pragma unroll
            for (int mt = 0; mt < 2; ++mt)
                #pragma unroll
                for (int nt = 0; nt < 2; ++nt)
                    acc[mt][nt] = __builtin_amdgcn_mfma_f32_16x16x32_bf16(
                        af[mt], bf[nt], acc[mt][nt], 0, 0, 0);
        }
    }

    #pragma unroll
    for (int mt = 0; mt < 2; ++mt)
        #pragma unroll
        for (int r = 0; r < 4; ++r) {
            int row = m0 + wm * 32 + mt * 16 + lg * 4 + r;
            #pragma unroll
            for (int nt = 0; nt < 2; ++nt) {
                int col = n0 + wn * 32 + nt * 16 + lr;
                C[(size_t)row * N + col] = acc[mt][nt][r] + bias[col];
            }
        }
}

// ---------------- causal flash attention, bf16 MFMA, split-K (CH=4) --------
// (round-7 version: QBLK=64)
__global__ __launch_bounds__(256) void attn_mfma_kernel(
    const bf16* __restrict__ Qp, const bf16* __restrict__ Kp,
    const bf16* __restrict__ Vtp, short* __restrict__ Yb,
    short* __restrict__ Opart, float* __restrict__ ml) {
    __shared__ __align__(16) short KsB[2][64 * 64];
    __shared__ __align__(16) short VtB[2][64 * 64];
    __shared__ __align__(16) short Pl[4][16 * 64];

    int tid = threadIdx.x;
    int w  = tid >> 6;
    int l  = tid & 63;
    int lr = l & 15;
    int lg = l >> 4;

    int job = (NJOBS - 1) - blockIdx.x;   // long-qi chunks dispatch first
    int h = job % NH;
    int u = job / NH;                     // 0..143
    int g = 0;
    while (u >= 2 * (g + 1) * (g + 2)) ++g;
    int v  = u - 2 * g * (g + 1);
    int jq = v / (g + 1);
    int qi = 4 * g + jq;
    int c0 = v - jq * (g + 1);
    int nch = g + 1;
    int kt0 = c0 * CH;
    int kt1 = kt0 + CH; if (kt1 > qi + 1) kt1 = qi + 1;
    int qt0 = qi * 64;

    const short* Qg  = (const short*)(Qp + (size_t)h * T_SEQ * HD);
    const short* Kg  = (const short*)(Kp + (size_t)h * T_SEQ * HD);
    const short* Vtg = (const short*)(Vtp + (size_t)h * HD * T_SEQ);

    int qrow = qt0 + w * 16 + lr;
    short8 qf0 = *(const short8*)(Qg + (size_t)qrow * HD + lg * 8);
    short8 qf1 = *(const short8*)(Qg + (size_t)qrow * HD + 32 + lg * 8);

    int srow = l >> 3;
    int cx   = (l & 7) ^ srow;            // inverse-swizzled source chunk

    auto stage = [&](int buf, int kt) {
        int k0 = kt * 64;
        #pragma unroll
        for (int e = 0; e < 2; ++e) {
            int r = e * 32 + w * 8 + srow;
            gload_lds16(Kg + (size_t)(k0 + r) * HD + cx * 8,
                        &KsB[buf][(e * 256 + w * 64) * 8]);
            gload_lds16(Vtg + (size_t)r * T_SEQ + k0 + cx * 8,
                        &VtB[buf][(e * 256 + w * 64) * 8]);
        }
    };

    f32x4 o[4] = {};
    float m = -INFINITY, lsum = 0.f;

    stage(0, kt0);

    for (int kt = kt0; kt < kt1; ++kt) {
        int cur = (kt - kt0) & 1;
        if (kt + 1 < kt1) {
            stage(1 - cur, kt + 1);
            asm volatile("s_waitcnt vmcnt(4)" ::: "memory");
        } else {
            asm volatile("s_waitcnt vmcnt(0)" ::: "memory");
        }
        __builtin_amdgcn_s_barrier();

        const short* Ks = KsB[cur];
        const short* Vt = VtB[cur];

        f32x4 c[4];
        #pragma unroll
        for (int mt = 0; mt < 4; ++mt) {
            c[mt] = (f32x4){0.f, 0.f, 0.f, 0.f};
            int row = mt * 16 + lr;
            #pragma unroll
            for (int ks = 0; ks < 2; ++ks) {
                short8 af = *(const short8*)(&Ks[row * 64 + (((ks * 4 + lg) ^ (row & 7)) << 3)]);
                c[mt] = __builtin_amdgcn_mfma_f32_16x16x32_bf16(af, ks ? qf1 : qf0, c[mt], 0, 0, 0);
            }
        }

        float p[16];
        float smax = -INFINITY;
        if (kt == qi) {                    // diagonal tile: causal mask
            int qg = qt0 + w * 16 + lr;
            int k0 = kt * 64;
            #pragma unroll
            for (int mt = 0; mt < 4; ++mt)
                #pragma unroll
                for (int r = 0; r < 4; ++r) {
                    float s = c[mt][r];
                    if (k0 + mt * 16 + lg * 4 + r > qg) s = -INFINITY;
                    p[mt * 4 + r] = s;
                    smax = fmaxf(smax, s);
                }
        } else {
            #pragma unroll
            for (int mt = 0; mt < 4; ++mt)
                #pragma unroll
                for (int r = 0; r < 4; ++r) {
                    float s = c[mt][r];
                    p[mt * 4 + r] = s;
                    smax = fmaxf(smax, s);
                }
        }
        smax = fmaxf(smax, __shfl_xor(smax, 16));
        smax = fmaxf(smax, __shfl_xor(smax, 32));
        float mnew = fmaxf(m, smax);
        float alpha = __expf(m - mnew);
        float ps = 0.f;
        #pragma unroll
        for (int i = 0; i < 16; ++i) { p[i] = __expf(p[i] - mnew); ps += p[i]; }
        ps += __shfl_xor(ps, 16);
        ps += __shfl_xor(ps, 32);
        lsum = lsum * alpha + ps;
        m = mnew;

        #pragma unroll
        for (int r = 0; r < 4; ++r) {
            float ar = __shfl(alpha, lg * 4 + r);
            #pragma unroll
            for (int nt = 0; nt < 4; ++nt) o[nt][r] *= ar;
        }

        short* Pw = &Pl[w][0];
        #pragma unroll
        for (int mt = 0; mt < 4; ++mt)
            #pragma unroll
            for (int rh = 0; rh < 2; ++rh) {
                unsigned int uu = f2bf(p[mt * 4 + 2 * rh]) | (f2bf(p[mt * 4 + 2 * rh + 1]) << 16);
                int chunk = 2 * mt + (lg >> 1);
                *(unsigned int*)(&Pw[lr * 64 + ((chunk ^ (lr & 7)) << 3)
                                     + 4 * (lg & 1) + 2 * rh]) = uu;
            }
        asm volatile("" ::: "memory");

        #pragma unroll
        for (int ks = 0; ks < 2; ++ks) {
            short8 pf = *(const short8*)(&Pw[lr * 64 + (((ks * 4 + lg) ^ (lr & 7)) << 3)]);
            #pragma unroll
            for (int nt = 0; nt < 4; ++nt) {
                int vrow = nt * 16 + lr;
                short8 vf = *(const short8*)(&Vt[vrow * 64 + (((ks * 4 + lg) ^ (vrow & 7)) << 3)]);
                o[nt] = __builtin_amdgcn_mfma_f32_16x16x32_bf16(pf, vf, o[nt], 0, 0, 0);
            }
        }
        __builtin_amdgcn_s_barrier();
    }

    if (nch == 1) {
        float invl = 1.f / lsum;
        #pragma unroll
        for (int r = 0; r < 4; ++r) {
            float ir = __shfl(invl, lg * 4 + r);
            int row = qt0 + w * 16 + lg * 4 + r;
            #pragma unroll
            for (int nt = 0; nt < 4; ++nt)
                Yb[(size_t)row * C_DIM + h * HD + nt * 16 + lr] =
                    (short)f2bf(o[nt][r] * ir);
        }
    } else {
        if (lg == 0) {
            ml[(size_t)job * 128 + w * 16 + lr] = m;
            ml[(size_t)job * 128 + 64 + w * 16 + lr] = lsum;
        }
        #pragma unroll
        for (int r = 0; r < 4; ++r) {
            int row = w * 16 + lg * 4 + r;
            #pragma unroll
            for (int nt = 0; nt < 4; ++nt)
                Opart[(size_t)job * 4096 + row * 64 + nt * 16 + lr] =
                    (short)f2bf(o[nt][r]);
        }
    }
}

// ---------------- combine split-K partials (qi >= 4, up to 8 chunks) -------
__global__ __launch_bounds__(256) void combine_kernel(
    const short* __restrict__ Opart, const float* __restrict__ ml,
    short* __restrict__ Yb) {
    int job = blockIdx.x;                 // 12 heads x 28 qi (4..31)
    int h  = job % NH;
    int qi = 4 + job / NH;
    int g  = qi >> 2;
    int nch = g + 1;
    int u0 = (g + 1) * (qi - 2 * g);

    int tid = threadIdx.x;
    int row = tid >> 2;
    int qp  = tid & 3;

    float mm[8], ll[8];
    float M = -INFINITY;
    #pragma unroll
    for (int c = 0; c < 8; ++c) {
        mm[c] = -INFINITY; ll[c] = 0.f;
        if (c < nch) {
            size_t pidx = (size_t)(u0 + c) * NH + h;
            mm[c] = ml[pidx * 128 + row];
            ll[c] = ml[pidx * 128 + 64 + row];
            M = fmaxf(M, mm[c]);
        }
    }
    float acc[16] = {};
    float L = 0.f;
    #pragma unroll
    for (int c = 0; c < 8; ++c) {
        if (c < nch) {
            float wgt = __expf(mm[c] - M);
            L += ll[c] * wgt;
            const short* op = Opart + ((size_t)(u0 + c) * NH + h) * 4096
                            + row * 64 + qp * 16;
            short8 a = *(const short8*)op;
            short8 b = *(const short8*)(op + 8);
            #pragma unroll
            for (int j = 0; j < 8; ++j) {
                acc[j]     += wgt * bf2f(a[j]);
                acc[8 + j] += wgt * bf2f(b[j]);
            }
        }
    }
    float invL = 1.f / L;
    short8 oa, ob;
    #pragma unroll
    for (int j = 0; j < 8; ++j) {
        oa[j] = (short)f2bf(acc[j] * invL);
        ob[j] = (short)f2bf(acc[8 + j] * invL);
    }
    short* dst = Yb + (size_t)(qi * 64 + row) * C_DIM + h * HD + qp * 16;
    *(short8*)dst = oa;
    *(short8*)(dst + 8) = ob;
}

extern "C" void kernel_launch(void* const* d_in, const int* in_sizes, int n_in,
                              void* d_out, int out_size, void* d_ws, size_t ws_size,
                              hipStream_t stream) {
    const float* x      = (const float*)d_in[0];
    const float* w_qkv  = (const float*)d_in[1];
    const float* b_qkv  = (const float*)d_in[2];
    const float* w_proj = (const float*)d_in[3];
    const float* b_proj = (const float*)d_in[4];
    float* out = (float*)d_out;

    float* ws = (float*)d_ws;
    short* yb     = (short*)ws;                 // 1,572,864 sh
    short* wprojT = (short*)(ws + 786432);      // 589,824 sh
    short* Opart  = (short*)(ws + 1081344);     // 1728*4096 sh
    float* mlbuf  = ws + 4620288;               // 1728*128 f
    short* Qh     = (short*)(ws + 4841472);     // 1,572,864 sh
    short* Kh     = (short*)(ws + 5627904);
    short* Vt     = (short*)(ws + 6414336);     // [h][d][t]
    float* ctab   = ws + 7200768;               // 65,536 f
    float* stab   = ws + 7266304;
    short* xb     = (short*)(ws + 7331840);     // 1,572,864 sh
    short* wqkvT  = (short*)(ws + 8118272);     // 1,769,472 sh

    prep_kernel<<<2368, 256, 0, stream>>>(x, w_qkv, w_proj, xb, wqkvT, wprojT,
                                          ctab, stab);

    dim3 g1(QKV_N / 128, T_SEQ / 128);
    gemm_qkv_rope_kernel<<<g1, 256, 0, stream>>>(xb, wqkvT, b_qkv, ctab, stab,
                                                 Qh, Kh, Vt);

    attn_mfma_kernel<<<NJOBS, 256, 0, stream>>>((const bf16*)Qh, (const bf16*)Kh,
                                                (const bf16*)Vt, yb, Opart, mlbuf);

    combine_kernel<<<NH * 28, 256, 0, stream>>>(Opart, mlbuf, yb);

    dim3 g4(C_DIM / 64, T_SEQ / 64);
    gemm_proj_kernel<<<g4, 256, 0, stream>>>(yb, wprojT, b_proj, out);
}

// Round 13
// 79.291 us; speedup vs baseline: 1.1550x; 1.1550x over previous
//
#include <hip/hip_runtime.h>
#include <hip/hip_bf16.h>
#include <math.h>

#define T_SEQ 2048
#define C_DIM 768
#define NH    12
#define HD    64
#define QKV_N 2304
#define CH    4          // kv-tiles per attention chunk (split-K)
#define NJOBS 1728       // 12 heads x 144 (qi,chunk) pairs

typedef __attribute__((ext_vector_type(8))) short short8;
typedef __attribute__((ext_vector_type(4))) short short4_t;
typedef __attribute__((ext_vector_type(4))) float f32x4;
typedef __hip_bfloat16 bf16;

static __device__ __forceinline__ unsigned int f2bf(float x) {
    bf16 b = __float2bfloat16(x);
    return (unsigned int)*reinterpret_cast<unsigned short*>(&b);
}
static __device__ __forceinline__ float bf2f(short u) {
    unsigned int v = ((unsigned int)(unsigned short)u) << 16;
    return *reinterpret_cast<float*>(&v);
}

static __device__ __forceinline__ void gload_lds16(const void* g, void* l) {
    __builtin_amdgcn_global_load_lds(
        (const __attribute__((address_space(1))) void*)g,
        (__attribute__((address_space(3))) void*)l, 16, 0, 0);
}

// ---------------- fused prep: convert x | transpose w_qkv | transpose w_proj
//                  | rope tables.  2368 blocks, range-dispatched. -----------
static __device__ __forceinline__ void transpose_tile(
    const float* __restrict__ W, short* __restrict__ Wt, int K, int N,
    int bx, int by, float* tile /* [64][65] */) {
    int k0 = by * 64, n0 = bx * 64;
    int tid = threadIdx.x;
    #pragma unroll
    for (int e = 0; e < 16; ++e) {
        int idx = e * 256 + tid;
        int r = idx >> 6, c = idx & 63;
        tile[r * 65 + c] = W[(size_t)(k0 + r) * N + n0 + c];
    }
    __syncthreads();
    #pragma unroll
    for (int e = 0; e < 16; ++e) {
        int idx = e * 256 + tid;
        int n = idx >> 6, k = idx & 63;
        Wt[(size_t)(n0 + n) * K + k0 + k] = (short)f2bf(tile[k * 65 + n]);
    }
}

__global__ __launch_bounds__(256) void prep_kernel(
    const float* __restrict__ x, const float* __restrict__ w_qkv,
    const float* __restrict__ w_proj, short* __restrict__ xb,
    short* __restrict__ wqkvT, short* __restrict__ wprojT,
    float* __restrict__ ctab, float* __restrict__ stab) {
    __shared__ float tile[64 * 65];
    int b = blockIdx.x;
    int tid = threadIdx.x;
    if (b < 1536) {                       // convert x -> bf16 (1536*1024 elems)
        int idx = (b * 256 + tid) * 4;
        float4 v = *(const float4*)(x + idx);
        short4_t o;
        o[0] = (short)f2bf(v.x); o[1] = (short)f2bf(v.y);
        o[2] = (short)f2bf(v.z); o[3] = (short)f2bf(v.w);
        *(short4_t*)(xb + idx) = o;
    } else if (b < 1968) {                // w_qkv [768][2304] -> [2304][768]
        int i = b - 1536;
        transpose_tile(w_qkv, wqkvT, C_DIM, QKV_N, i % 36, i / 36, tile);
    } else if (b < 2112) {                // w_proj [768][768] -> [768][768]^T
        int i = b - 1968;
        transpose_tile(w_proj, wprojT, C_DIM, C_DIM, i % 12, i / 12, tile);
    } else {                              // rope tables (256 blocks)
        int idx = (b - 2112) * 256 + tid;
        int p = idx >> 5;
        int i = idx & 31;
        float invf = exp2f(-(float)i * (0.03125f * 13.287712379549449f));
        float f = (float)p * invf;
        ctab[idx] = cosf(f);
        stab[idx] = sinf(f);
    }
}

// ---------------- fused QKV GEMM + bias + RoPE + head-split + V-transpose --
// R7 structure (128x128, BK=64, 130-slot padded LDS) + T1 XCD-aware block
// swizzle: 288 blocks, 1-D grid; each XCD gets 36 consecutive tiles = 2 full
// 18-wide row-panels -> A-panel (192 KB) is reused 18x from that XCD's L2
// instead of L3. Staging is the bandwidth bottleneck (R12 post-mortem).
__global__ __launch_bounds__(256) void gemm_qkv_rope_kernel(
    const short* __restrict__ A, const short* __restrict__ Bt,
    const float* __restrict__ bias, const float* __restrict__ ctab,
    const float* __restrict__ stab, short* __restrict__ Qout,
    short* __restrict__ Kout, short* __restrict__ Vtout) {
    __shared__ __align__(16) short smem[2 * 8 * 130 * 8];
    short* As = smem;
    short* Bs = smem + 8 * 130 * 8;
    int tid = threadIdx.x;
    int w = tid >> 6, l = tid & 63;
    int lr = l & 15, lg = l >> 4;
    int wm = w >> 1, wn = w & 1;
    // XCD swizzle (bijective: 288 % 8 == 0, 36 tiles per XCD)
    int id  = blockIdx.x;
    int id2 = (id & 7) * 36 + (id >> 3);
    int bx  = id2 % 18, by = id2 / 18;
    int m0 = by * 128, n0 = bx * 128;
    const int K = C_DIM;

    f32x4 acc[4][4] = {};

    for (int k0 = 0; k0 < K; k0 += 64) {
        __syncthreads();
        #pragma unroll
        for (int e = 0; e < 4; ++e) {
            int u = w * 4 + e;
            int kc = u >> 1, r0 = (u & 1) * 64;
            const short* srcA = A  + (size_t)(m0 + r0 + l) * K + k0 + kc * 8;
            const short* srcB = Bt + (size_t)(n0 + r0 + l) * K + k0 + kc * 8;
            gload_lds16(srcA, &As[(kc * 130 + r0) * 8]);
            gload_lds16(srcB, &Bs[(kc * 130 + r0) * 8]);
        }
        __syncthreads();
        #pragma unroll
        for (int ks = 0; ks < 2; ++ks) {
            short8 af[4], bf[4];
            #pragma unroll
            for (int mt = 0; mt < 4; ++mt)
                af[mt] = *(const short8*)&As[((ks * 4 + lg) * 130 + wm * 64 + mt * 16 + lr) * 8];
            #pragma unroll
            for (int nt = 0; nt < 4; ++nt)
                bf[nt] = *(const short8*)&Bs[((ks * 4 + lg) * 130 + wn * 64 + nt * 16 + lr) * 8];
            #pragma unroll
            for (int mt = 0; mt < 4; ++mt)
                #pragma unroll
                for (int nt = 0; nt < 4; ++nt)
                    acc[mt][nt] = __builtin_amdgcn_mfma_f32_16x16x32_bf16(
                        af[mt], bf[nt], acc[mt][nt], 0, 0, 0);
        }
    }

    __syncthreads();   // all waves done with As/Bs before V-scratch reuse

    int nc0 = n0 + wn * 64;            // wave's column base (one head)
    int tensor = nc0 / 768;            // 0=Q 1=K 2=V (uniform per wave)
    int h = (nc0 - tensor * 768) >> 6;
    int t0g = m0 + wm * 64;

    float bv[4];
    #pragma unroll
    for (int nt = 0; nt < 4; ++nt) bv[nt] = bias[nc0 + nt * 16 + lr];

    if (tensor < 2) {
        short* dst = (tensor == 0 ? Qout : Kout) + (size_t)h * T_SEQ * HD;
        float qs = (tensor == 0) ? 0.125f : 1.0f;
        #pragma unroll
        for (int mt = 0; mt < 4; ++mt)
            #pragma unroll
            for (int r = 0; r < 4; ++r) {
                int t = t0g + mt * 16 + lg * 4 + r;
                #pragma unroll
                for (int nt = 0; nt < 2; ++nt) {
                    int i = nt * 16 + lr;          // 0..31
                    float c = ctab[t * 32 + i];
                    float s = stab[t * 32 + i];
                    float lo = acc[mt][nt][r]     + bv[nt];
                    float hi = acc[mt][nt + 2][r] + bv[nt + 2];
                    dst[(size_t)t * HD + i]      = (short)f2bf((lo * c - hi * s) * qs);
                    dst[(size_t)t * HD + i + 32] = (short)f2bf((hi * c + lo * s) * qs);
                }
            }
    } else {
        // V: transpose 64x64 wave tile via per-wave LDS scratch region
        // (w*4096 + 4096 <= 16384 < 20800, inside the single smem array).
        short* S = smem + w * 4096;
        #pragma unroll
        for (int mt = 0; mt < 4; ++mt)
            #pragma unroll
            for (int nt = 0; nt < 4; ++nt) {
                int d = nt * 16 + lr;
                #pragma unroll
                for (int r = 0; r < 4; ++r) {
                    int tl = mt * 16 + lg * 4 + r;
                    float v = acc[mt][nt][r] + bv[nt];
                    S[d * 64 + ((tl & 7) | (((tl >> 3) ^ (d & 7)) << 3))] =
                        (short)f2bf(v);
                }
            }
        asm volatile("s_waitcnt lgkmcnt(0)" ::: "memory");
        int cc = l & 7, db = l >> 3;
        #pragma unroll
        for (int i = 0; i < 8; ++i) {
            int d = db + i * 8;
            short8 v = *(const short8*)&S[d * 64 + ((cc ^ (d & 7)) << 3)];
            *(short8*)(Vtout + ((size_t)h * HD + d) * T_SEQ + t0g + cc * 8) = v;
        }
    }
}

// ---------------- proj GEMM, 64x64 tile, 384 blocks + XCD swizzle ----------
__global__ __launch_bounds__(256) void gemm_proj_kernel(
    const short* __restrict__ A, const short* __restrict__ Bt,
    const float* __restrict__ bias, float* __restrict__ C) {
    const int K = C_DIM, N = C_DIM;
    __shared__ __align__(16) short As[8 * 66 * 8];
    __shared__ __align__(16) short Bs[8 * 66 * 8];
    int tid = threadIdx.x;
    int w = tid >> 6, l = tid & 63;
    int lr = l & 15, lg = l >> 4;
    int wm = w >> 1, wn = w & 1;
    // XCD swizzle (384 % 8 == 0, 48 tiles per XCD = 4 full 12-wide panels)
    int id  = blockIdx.x;
    int id2 = (id & 7) * 48 + (id >> 3);
    int bx  = id2 % 12, by = id2 / 12;
    int m0 = by * 64, n0 = bx * 64;

    f32x4 acc[2][2] = {};

    for (int k0 = 0; k0 < K; k0 += 64) {
        __syncthreads();
        #pragma unroll
        for (int e = 0; e < 2; ++e) {
            int kc = w * 2 + e;                 // wave-uniform dest base
            gload_lds16(A  + (size_t)(m0 + l) * K + k0 + kc * 8, &As[kc * 66 * 8]);
            gload_lds16(Bt + (size_t)(n0 + l) * K + k0 + kc * 8, &Bs[kc * 66 * 8]);
        }
        __syncthreads();
        #pragma unroll
        for (int ks = 0; ks < 2; ++ks) {
            short8 af[2], bf[2];
            #pragma unroll
            for (int mt = 0; mt < 2; ++mt)
                af[mt] = *(const short8*)&As[((ks * 4 + lg) * 66 + wm * 32 + mt * 16 + lr) * 8];
            #pragma unroll
            for (int nt = 0; nt < 2; ++nt)
                bf[nt] = *(const short8*)&Bs[((ks * 4 + lg) * 66 + wn * 32 + nt * 16 + lr) * 8];
            #pragma unroll
            for (int mt = 0; mt < 2; ++mt)
                #pragma unroll
                for (int nt = 0; nt < 2; ++nt)
                    acc[mt][nt] = __builtin_amdgcn_mfma_f32_16x16x32_bf16(
                        af[mt], bf[nt], acc[mt][nt], 0, 0, 0);
        }
    }

    #pragma unroll
    for (int mt = 0; mt < 2; ++mt)
        #pragma unroll
        for (int r = 0; r < 4; ++r) {
            int row = m0 + wm * 32 + mt * 16 + lg * 4 + r;
            #pragma unroll
            for (int nt = 0; nt < 2; ++nt) {
                int col = n0 + wn * 32 + nt * 16 + lr;
                C[(size_t)row * N + col] = acc[mt][nt][r] + bias[col];
            }
        }
}

// ---------------- causal flash attention, bf16 MFMA, split-K (CH=4) --------
// (round-7 version: QBLK=64)
__global__ __launch_bounds__(256) void attn_mfma_kernel(
    const bf16* __restrict__ Qp, const bf16* __restrict__ Kp,
    const bf16* __restrict__ Vtp, short* __restrict__ Yb,
    short* __restrict__ Opart, float* __restrict__ ml) {
    __shared__ __align__(16) short KsB[2][64 * 64];
    __shared__ __align__(16) short VtB[2][64 * 64];
    __shared__ __align__(16) short Pl[4][16 * 64];

    int tid = threadIdx.x;
    int w  = tid >> 6;
    int l  = tid & 63;
    int lr = l & 15;
    int lg = l >> 4;

    int job = (NJOBS - 1) - blockIdx.x;   // long-qi chunks dispatch first
    int h = job % NH;
    int u = job / NH;                     // 0..143
    int g = 0;
    while (u >= 2 * (g + 1) * (g + 2)) ++g;
    int v  = u - 2 * g * (g + 1);
    int jq = v / (g + 1);
    int qi = 4 * g + jq;
    int c0 = v - jq * (g + 1);
    int nch = g + 1;
    int kt0 = c0 * CH;
    int kt1 = kt0 + CH; if (kt1 > qi + 1) kt1 = qi + 1;
    int qt0 = qi * 64;

    const short* Qg  = (const short*)(Qp + (size_t)h * T_SEQ * HD);
    const short* Kg  = (const short*)(Kp + (size_t)h * T_SEQ * HD);
    const short* Vtg = (const short*)(Vtp + (size_t)h * HD * T_SEQ);

    int qrow = qt0 + w * 16 + lr;
    short8 qf0 = *(const short8*)(Qg + (size_t)qrow * HD + lg * 8);
    short8 qf1 = *(const short8*)(Qg + (size_t)qrow * HD + 32 + lg * 8);

    int srow = l >> 3;
    int cx   = (l & 7) ^ srow;            // inverse-swizzled source chunk

    auto stage = [&](int buf, int kt) {
        int k0 = kt * 64;
        #pragma unroll
        for (int e = 0; e < 2; ++e) {
            int r = e * 32 + w * 8 + srow;
            gload_lds16(Kg + (size_t)(k0 + r) * HD + cx * 8,
                        &KsB[buf][(e * 256 + w * 64) * 8]);
            gload_lds16(Vtg + (size_t)r * T_SEQ + k0 + cx * 8,
                        &VtB[buf][(e * 256 + w * 64) * 8]);
        }
    };

    f32x4 o[4] = {};
    float m = -INFINITY, lsum = 0.f;

    stage(0, kt0);

    for (int kt = kt0; kt < kt1; ++kt) {
        int cur = (kt - kt0) & 1;
        if (kt + 1 < kt1) {
            stage(1 - cur, kt + 1);
            asm volatile("s_waitcnt vmcnt(4)" ::: "memory");
        } else {
            asm volatile("s_waitcnt vmcnt(0)" ::: "memory");
        }
        __builtin_amdgcn_s_barrier();

        const short* Ks = KsB[cur];
        const short* Vt = VtB[cur];

        f32x4 c[4];
        #pragma unroll
        for (int mt = 0; mt < 4; ++mt) {
            c[mt] = (f32x4){0.f, 0.f, 0.f, 0.f};
            int row = mt * 16 + lr;
            #pragma unroll
            for (int ks = 0; ks < 2; ++ks) {
                short8 af = *(const short8*)(&Ks[row * 64 + (((ks * 4 + lg) ^ (row & 7)) << 3)]);
                c[mt] = __builtin_amdgcn_mfma_f32_16x16x32_bf16(af, ks ? qf1 : qf0, c[mt], 0, 0, 0);
            }
        }

        float p[16];
        float smax = -INFINITY;
        if (kt == qi) {                    // diagonal tile: causal mask
            int qg = qt0 + w * 16 + lr;
            int k0 = kt * 64;
            #pragma unroll
            for (int mt = 0; mt < 4; ++mt)
                #pragma unroll
                for (int r = 0; r < 4; ++r) {
                    float s = c[mt][r];
                    if (k0 + mt * 16 + lg * 4 + r > qg) s = -INFINITY;
                    p[mt * 4 + r] = s;
                    smax = fmaxf(smax, s);
                }
        } else {
            #pragma unroll
            for (int mt = 0; mt < 4; ++mt)
                #pragma unroll
                for (int r = 0; r < 4; ++r) {
                    float s = c[mt][r];
                    p[mt * 4 + r] = s;
                    smax = fmaxf(smax, s);
                }
        }
        smax = fmaxf(smax, __shfl_xor(smax, 16));
        smax = fmaxf(smax, __shfl_xor(smax, 32));
        float mnew = fmaxf(m, smax);
        float alpha = __expf(m - mnew);
        float ps = 0.f;
        #pragma unroll
        for (int i = 0; i < 16; ++i) { p[i] = __expf(p[i] - mnew); ps += p[i]; }
        ps += __shfl_xor(ps, 16);
        ps += __shfl_xor(ps, 32);
        lsum = lsum * alpha + ps;
        m = mnew;

        #pragma unroll
        for (int r = 0; r < 4; ++r) {
            float ar = __shfl(alpha, lg * 4 + r);
            #pragma unroll
            for (int nt = 0; nt < 4; ++nt) o[nt][r] *= ar;
        }

        short* Pw = &Pl[w][0];
        #pragma unroll
        for (int mt = 0; mt < 4; ++mt)
            #pragma unroll
            for (int rh = 0; rh < 2; ++rh) {
                unsigned int uu = f2bf(p[mt * 4 + 2 * rh]) | (f2bf(p[mt * 4 + 2 * rh + 1]) << 16);
                int chunk = 2 * mt + (lg >> 1);
                *(unsigned int*)(&Pw[lr * 64 + ((chunk ^ (lr & 7)) << 3)
                                     + 4 * (lg & 1) + 2 * rh]) = uu;
            }
        asm volatile("" ::: "memory");

        #pragma unroll
        for (int ks = 0; ks < 2; ++ks) {
            short8 pf = *(const short8*)(&Pw[lr * 64 + (((ks * 4 + lg) ^ (lr & 7)) << 3)]);
            #pragma unroll
            for (int nt = 0; nt < 4; ++nt) {
                int vrow = nt * 16 + lr;
                short8 vf = *(const short8*)(&Vt[vrow * 64 + (((ks * 4 + lg) ^ (vrow & 7)) << 3)]);
                o[nt] = __builtin_amdgcn_mfma_f32_16x16x32_bf16(pf, vf, o[nt], 0, 0, 0);
            }
        }
        __builtin_amdgcn_s_barrier();
    }

    if (nch == 1) {
        float invl = 1.f / lsum;
        #pragma unroll
        for (int r = 0; r < 4; ++r) {
            float ir = __shfl(invl, lg * 4 + r);
            int row = qt0 + w * 16 + lg * 4 + r;
            #pragma unroll
            for (int nt = 0; nt < 4; ++nt)
                Yb[(size_t)row * C_DIM + h * HD + nt * 16 + lr] =
                    (short)f2bf(o[nt][r] * ir);
        }
    } else {
        if (lg == 0) {
            ml[(size_t)job * 128 + w * 16 + lr] = m;
            ml[(size_t)job * 128 + 64 + w * 16 + lr] = lsum;
        }
        #pragma unroll
        for (int r = 0; r < 4; ++r) {
            int row = w * 16 + lg * 4 + r;
            #pragma unroll
            for (int nt = 0; nt < 4; ++nt)
                Opart[(size_t)job * 4096 + row * 64 + nt * 16 + lr] =
                    (short)f2bf(o[nt][r]);
        }
    }
}

// ---------------- combine split-K partials (qi >= 4, up to 8 chunks) -------
__global__ __launch_bounds__(256) void combine_kernel(
    const short* __restrict__ Opart, const float* __restrict__ ml,
    short* __restrict__ Yb) {
    int job = blockIdx.x;                 // 12 heads x 28 qi (4..31)
    int h  = job % NH;
    int qi = 4 + job / NH;
    int g  = qi >> 2;
    int nch = g + 1;
    int u0 = (g + 1) * (qi - 2 * g);

    int tid = threadIdx.x;
    int row = tid >> 2;
    int qp  = tid & 3;

    float mm[8], ll[8];
    float M = -INFINITY;
    #pragma unroll
    for (int c = 0; c < 8; ++c) {
        mm[c] = -INFINITY; ll[c] = 0.f;
        if (c < nch) {
            size_t pidx = (size_t)(u0 + c) * NH + h;
            mm[c] = ml[pidx * 128 + row];
            ll[c] = ml[pidx * 128 + 64 + row];
            M = fmaxf(M, mm[c]);
        }
    }
    float acc[16] = {};
    float L = 0.f;
    #pragma unroll
    for (int c = 0; c < 8; ++c) {
        if (c < nch) {
            float wgt = __expf(mm[c] - M);
            L += ll[c] * wgt;
            const short* op = Opart + ((size_t)(u0 + c) * NH + h) * 4096
                            + row * 64 + qp * 16;
            short8 a = *(const short8*)op;
            short8 b = *(const short8*)(op + 8);
            #pragma unroll
            for (int j = 0; j < 8; ++j) {
                acc[j]     += wgt * bf2f(a[j]);
                acc[8 + j] += wgt * bf2f(b[j]);
            }
        }
    }
    float invL = 1.f / L;
    short8 oa, ob;
    #pragma unroll
    for (int j = 0; j < 8; ++j) {
        oa[j] = (short)f2bf(acc[j] * invL);
        ob[j] = (short)f2bf(acc[8 + j] * invL);
    }
    short* dst = Yb + (size_t)(qi * 64 + row) * C_DIM + h * HD + qp * 16;
    *(short8*)dst = oa;
    *(short8*)(dst + 8) = ob;
}

extern "C" void kernel_launch(void* const* d_in, const int* in_sizes, int n_in,
                              void* d_out, int out_size, void* d_ws, size_t ws_size,
                              hipStream_t stream) {
    const float* x      = (const float*)d_in[0];
    const float* w_qkv  = (const float*)d_in[1];
    const float* b_qkv  = (const float*)d_in[2];
    const float* w_proj = (const float*)d_in[3];
    const float* b_proj = (const float*)d_in[4];
    float* out = (float*)d_out;

    float* ws = (float*)d_ws;
    short* yb     = (short*)ws;                 // 1,572,864 sh
    short* wprojT = (short*)(ws + 786432);      // 589,824 sh
    short* Opart  = (short*)(ws + 1081344);     // 1728*4096 sh
    float* mlbuf  = ws + 4620288;               // 1728*128 f
    short* Qh     = (short*)(ws + 4841472);     // 1,572,864 sh
    short* Kh     = (short*)(ws + 5627904);
    short* Vt     = (short*)(ws + 6414336);     // [h][d][t]
    float* ctab   = ws + 7200768;               // 65,536 f
    float* stab   = ws + 7266304;
    short* xb     = (short*)(ws + 7331840);     // 1,572,864 sh
    short* wqkvT  = (short*)(ws + 8118272);     // 1,769,472 sh

    prep_kernel<<<2368, 256, 0, stream>>>(x, w_qkv, w_proj, xb, wqkvT, wprojT,
                                          ctab, stab);

    gemm_qkv_rope_kernel<<<288, 256, 0, stream>>>(xb, wqkvT, b_qkv, ctab, stab,
                                                  Qh, Kh, Vt);

    attn_mfma_kernel<<<NJOBS, 256, 0, stream>>>((const bf16*)Qh, (const bf16*)Kh,
                                                (const bf16*)Vt, yb, Opart, mlbuf);

    combine_kernel<<<NH * 28, 256, 0, stream>>>(Opart, mlbuf, yb);

    gemm_proj_kernel<<<384, 256, 0, stream>>>(yb, wprojT, b_proj, out);
}